// Round 1
// baseline (447.839 us; speedup 1.0000x reference)
//
#include <hip/hip_runtime.h>
#include <hip/hip_bf16.h>

// CausalDiscoveryModule: B=256, N=512, E=32, IN=512, K=10
// out[b,i,j] = gate_b * sigmoid(logit) on per-(b,i)-row top-10 of j, else 0
// logit = sum_e (c_b^2 * emb_i)[e] * emb_j[e]

#define NUM_VARS 512
#define EMBED_DIM 32
#define IN_DIM 512
#define BATCH 256

// ---------------- K1: context MLP -> w = c^2 [256][32], gate [256] ----------
__global__ __launch_bounds__(256) void cdm_k1(
    const float* __restrict__ ctx, const float* __restrict__ W1,
    const float* __restrict__ b1, const float* __restrict__ W2,
    const float* __restrict__ b2, const float* __restrict__ Wg,
    const float* __restrict__ bg, float* __restrict__ wws,
    float* __restrict__ gws) {
  const int bb = blockIdx.x;
  const int t = threadIdx.x;
  __shared__ float xs[512];
  __shared__ float psum[32][9];   // +1 pad
  __shared__ float hs[32];
  __shared__ float cs[32];
  const float* x = ctx + (bb << 9);
  xs[t] = x[t];
  xs[t + 256] = x[t + 256];
  __syncthreads();
  {
    const int e = t >> 3, part = t & 7;
    const float* wrow = W1 + e * 512 + part * 64;
    const float* xp = xs + part * 64;
    float a = 0.f;
#pragma unroll
    for (int m = 0; m < 64; ++m) a = fmaf(wrow[m], xp[m], a);
    psum[e][part] = a;
  }
  __syncthreads();
  if (t < 32) {
    float a = 0.f;
#pragma unroll
    for (int p = 0; p < 8; ++p) a += psum[t][p];
    hs[t] = fmaxf(a + b1[t], 0.f);
  }
  __syncthreads();
  if (t < 32) {
    const float* wrow = W2 + (t << 5);
    float a = 0.f;
#pragma unroll
    for (int k = 0; k < 32; ++k) a = fmaf(wrow[k], hs[k], a);
    float c = a + b2[t];
    cs[t] = c;
    wws[(bb << 5) + t] = c * c;
  }
  __syncthreads();
  if (t == 0) {
    float a = 0.f;
#pragma unroll
    for (int k = 0; k < 32; ++k) a = fmaf(Wg[k], cs[k], a);
    float g = a + bg[0];
    gws[bb] = 1.f / (1.f + __expf(-g));
  }
}

// ---------------- K2: lane-per-row logits + exact top-10 + masked write -----
__global__ __launch_bounds__(256, 2) void cdm_k2(
    const float* __restrict__ emb, const float* __restrict__ wws,
    const float* __restrict__ gws, float* __restrict__ out) {
  const int lane = threadIdx.x & 63;
  const int wid = (blockIdx.x << 2) + (threadIdx.x >> 6);  // 2048 waves
  const int r0 = wid << 6;          // 64 rows per wave, same b
  const int row = r0 + lane;
  const int b = r0 >> 9;
  const int i = row & 511;

  __shared__ float sbuf_all[4][4096];  // 16KB per wave -> 64KB/block
  float* sb = sbuf_all[threadIdx.x >> 6];

  // sv[e] = (c^2)[b][e] * emb[i][e]  (per-lane)
  float sv[32];
  {
    const float4* wb = reinterpret_cast<const float4*>(wws + (b << 5));
    const float4* ei = reinterpret_cast<const float4*>(emb + (i << 5));
#pragma unroll
    for (int q = 0; q < 8; ++q) {
      float4 a = wb[q];
      float4 xv = ei[q];
      sv[4 * q + 0] = a.x * xv.x;
      sv[4 * q + 1] = a.y * xv.y;
      sv[4 * q + 2] = a.z * xv.z;
      sv[4 * q + 3] = a.w * xv.w;
    }
  }
  const float gateb = gws[b];

  // top-10 (value desc; ascending-j arrival => exact tie semantics)
  float hv[10];
  int hj[10];
#pragma unroll
  for (int k = 0; k < 10; ++k) { hv[k] = -1e30f; hj[k] = 0; }

  for (int j0 = 0; j0 < 512; j0 += 4) {
    float a0 = 0.f, a1 = 0.f, a2 = 0.f, a3 = 0.f;
    const float4* e0 = reinterpret_cast<const float4*>(emb + ((j0 + 0) << 5));
    const float4* e1 = reinterpret_cast<const float4*>(emb + ((j0 + 1) << 5));
    const float4* e2 = reinterpret_cast<const float4*>(emb + ((j0 + 2) << 5));
    const float4* e3 = reinterpret_cast<const float4*>(emb + ((j0 + 3) << 5));
#pragma unroll
    for (int q = 0; q < 8; ++q) {
      float4 v0 = e0[q], v1 = e1[q], v2 = e2[q], v3 = e3[q];
      // e-sequential FMA chains (match BLAS-style k-sequential accumulation)
      a0 = fmaf(sv[4 * q + 0], v0.x, a0);
      a0 = fmaf(sv[4 * q + 1], v0.y, a0);
      a0 = fmaf(sv[4 * q + 2], v0.z, a0);
      a0 = fmaf(sv[4 * q + 3], v0.w, a0);
      a1 = fmaf(sv[4 * q + 0], v1.x, a1);
      a1 = fmaf(sv[4 * q + 1], v1.y, a1);
      a1 = fmaf(sv[4 * q + 2], v1.z, a1);
      a1 = fmaf(sv[4 * q + 3], v1.w, a1);
      a2 = fmaf(sv[4 * q + 0], v2.x, a2);
      a2 = fmaf(sv[4 * q + 1], v2.y, a2);
      a2 = fmaf(sv[4 * q + 2], v2.z, a2);
      a2 = fmaf(sv[4 * q + 3], v2.w, a2);
      a3 = fmaf(sv[4 * q + 0], v3.x, a3);
      a3 = fmaf(sv[4 * q + 1], v3.y, a3);
      a3 = fmaf(sv[4 * q + 2], v3.z, a3);
      a3 = fmaf(sv[4 * q + 3], v3.w, a3);
    }

    const float thr = hv[9];
    int p0 = a0 > thr, p1 = a1 > thr, p2 = a2 > thr, p3 = a3 > thr;
    while (__any(p0 | p1 | p2 | p3)) {
      if (p0 | p1 | p2 | p3) {
        float v;
        int jn;
        if (p0) { v = a0; jn = j0; p0 = 0; }
        else if (p1) { v = a1; jn = j0 + 1; p1 = 0; }
        else if (p2) { v = a2; jn = j0 + 2; p2 = 0; }
        else { v = a3; jn = j0 + 3; p3 = 0; }
        // shift-insert (strict >): equal values keep earlier (lower-j) above
#pragma unroll
        for (int k = 9; k >= 1; --k) {
          bool gk = v > hv[k];
          bool gk1 = v > hv[k - 1];
          hv[k] = gk ? (gk1 ? hv[k - 1] : v) : hv[k];
          hj[k] = gk ? (gk1 ? hj[k - 1] : jn) : hj[k];
        }
        bool g0 = v > hv[0];
        hv[0] = g0 ? v : hv[0];
        hj[0] = g0 ? jn : hj[0];
      }
      const float nt = hv[9];
      p0 = p0 && (a0 > nt);
      p1 = p1 && (a1 > nt);
      p2 = p2 && (a2 > nt);
      p3 = p3 && (a3 > nt);
    }
  }

  // epilogue: sigmoid on the 10 survivors, LDS-assembled coalesced writes
  float oval[10];
#pragma unroll
  for (int k = 0; k < 10; ++k) oval[k] = gateb / (1.f + __expf(-hv[k]));

  float4 z4;
  z4.x = 0.f; z4.y = 0.f; z4.z = 0.f; z4.w = 0.f;
  float4* sb4 = reinterpret_cast<float4*>(sb);
  const int lrow = lane & 7;
  for (int t8 = 0; t8 < 8; ++t8) {  // 8 batches x 8 rows
    asm volatile("s_waitcnt lgkmcnt(0)" ::: "memory");
#pragma unroll
    for (int k = 0; k < 16; ++k) sb4[(k << 6) + lane] = z4;
    asm volatile("s_waitcnt lgkmcnt(0)" ::: "memory");
    if ((lane >> 3) == t8) {
#pragma unroll
      for (int k = 0; k < 10; ++k) sb[(lrow << 9) + hj[k]] = oval[k];
    }
    asm volatile("s_waitcnt lgkmcnt(0)" ::: "memory");
    float4* og = reinterpret_cast<float4*>(out + ((size_t)r0 << 9) +
                                           ((size_t)t8 << 12));
#pragma unroll
    for (int k = 0; k < 16; ++k) og[(k << 6) + lane] = sb4[(k << 6) + lane];
  }
}

extern "C" void kernel_launch(void* const* d_in, const int* in_sizes, int n_in,
                              void* d_out, int out_size, void* d_ws,
                              size_t ws_size, hipStream_t stream) {
  const float* ctx = (const float*)d_in[0];
  const float* emb = (const float*)d_in[1];
  const float* W1 = (const float*)d_in[2];
  const float* b1 = (const float*)d_in[3];
  const float* W2 = (const float*)d_in[4];
  const float* b2 = (const float*)d_in[5];
  const float* Wg = (const float*)d_in[6];
  const float* bg = (const float*)d_in[7];
  float* out = (float*)d_out;
  float* wws = (float*)d_ws;            // 256*32 floats: c^2
  float* gws = wws + BATCH * EMBED_DIM; // 256 floats: gate

  cdm_k1<<<BATCH, 256, 0, stream>>>(ctx, W1, b1, W2, b2, Wg, bg, wws, gws);
  cdm_k2<<<512, 256, 0, stream>>>(emb, wws, gws, out);
}

// Round 3
// 391.383 us; speedup vs baseline: 1.1442x; 1.1442x over previous
//
#include <hip/hip_runtime.h>
#include <hip/hip_bf16.h>

// CausalDiscoveryModule: B=256, N=512, E=32, IN=512, K=10
// out[b,i,j] = gate_b * sigmoid(logit) on per-(b,i)-row top-10 of j, else 0
// logit = sum_e (c_b^2 * emb_i)[e] * emb_j[e]
//
// R3 = R2 with the nontemporal-store type fixed (native clang vector type).
// R2: wave-pair j-split (wave h=0 scans j<256, h=1 scans j>=256) -> 4096
// waves (16/CU) instead of 2048 (8/CU); LDS merge of the two top-10 lists
// with exact jax tie semantics; 32KB LDS/block; nontemporal output stores.

#define NUM_VARS 512
#define EMBED_DIM 32
#define IN_DIM 512
#define BATCH 256

typedef float nf4 __attribute__((ext_vector_type(4)));  // NT-store friendly

// ---------------- K1: context MLP -> w = c^2 [256][32], gate [256] ----------
__global__ __launch_bounds__(256) void cdm_k1(
    const float* __restrict__ ctx, const float* __restrict__ W1,
    const float* __restrict__ b1, const float* __restrict__ W2,
    const float* __restrict__ b2, const float* __restrict__ Wg,
    const float* __restrict__ bg, float* __restrict__ wws,
    float* __restrict__ gws) {
  const int bb = blockIdx.x;
  const int t = threadIdx.x;
  __shared__ float xs[512];
  __shared__ float psum[32][9];   // +1 pad
  __shared__ float hs[32];
  __shared__ float cs[32];
  const float* x = ctx + (bb << 9);
  xs[t] = x[t];
  xs[t + 256] = x[t + 256];
  __syncthreads();
  {
    const int e = t >> 3, part = t & 7;
    const float* wrow = W1 + e * 512 + part * 64;
    const float* xp = xs + part * 64;
    float a = 0.f;
#pragma unroll
    for (int m = 0; m < 64; ++m) a = fmaf(wrow[m], xp[m], a);
    psum[e][part] = a;
  }
  __syncthreads();
  if (t < 32) {
    float a = 0.f;
#pragma unroll
    for (int p = 0; p < 8; ++p) a += psum[t][p];
    hs[t] = fmaxf(a + b1[t], 0.f);
  }
  __syncthreads();
  if (t < 32) {
    const float* wrow = W2 + (t << 5);
    float a = 0.f;
#pragma unroll
    for (int k = 0; k < 32; ++k) a = fmaf(wrow[k], hs[k], a);
    float c = a + b2[t];
    cs[t] = c;
    wws[(bb << 5) + t] = c * c;
  }
  __syncthreads();
  if (t == 0) {
    float a = 0.f;
#pragma unroll
    for (int k = 0; k < 32; ++k) a = fmaf(Wg[k], cs[k], a);
    float g = a + bg[0];
    gws[bb] = 1.f / (1.f + __expf(-g));
  }
}

// strict-> shift insert: equal values keep earlier-inserted (lower j) above
#define TOP10_INSERT(v, jn)                                   \
  do {                                                        \
    _Pragma("unroll") for (int k = 9; k >= 1; --k) {          \
      bool gk = (v) > hv[k];                                  \
      bool gk1 = (v) > hv[k - 1];                             \
      hv[k] = gk ? (gk1 ? hv[k - 1] : (v)) : hv[k];           \
      hj[k] = gk ? (gk1 ? hj[k - 1] : (jn)) : hj[k];          \
    }                                                         \
    bool g0 = (v) > hv[0];                                    \
    hv[0] = g0 ? (v) : hv[0];                                 \
    hj[0] = g0 ? (jn) : hj[0];                                \
  } while (0)

// ---------------- K2: wave-pair per 64 rows; exact top-10; masked write -----
__global__ __launch_bounds__(256, 4) void cdm_k2(
    const float* __restrict__ emb, const float* __restrict__ wws,
    const float* __restrict__ gws, float* __restrict__ out) {
  const int lane = threadIdx.x & 63;
  const int wv = threadIdx.x >> 6;   // 0..3
  const int grp = wv >> 1;           // row-group within block
  const int half = wv & 1;           // 0: j in [0,256), 1: [256,512)
  const int G = __builtin_amdgcn_readfirstlane((blockIdx.x << 1) + grp);
  const int r0 = G << 6;             // 64 rows per group, same b
  const int b = r0 >> 9;
  const int i = (r0 + lane) & 511;
  const int jbase = __builtin_amdgcn_readfirstlane(half << 8);

  __shared__ float sbuf[2][4096];    // 16KB per group -> 32KB/block
  float* sb = sbuf[grp];

  // sv[e] = (c^2)[b][e] * emb[i][e]  (per-lane)
  float sv[32];
  {
    const float4* wb = reinterpret_cast<const float4*>(wws + (b << 5));
    const float4* ei = reinterpret_cast<const float4*>(emb + (i << 5));
#pragma unroll
    for (int q = 0; q < 8; ++q) {
      float4 a = wb[q];
      float4 xv = ei[q];
      sv[4 * q + 0] = a.x * xv.x;
      sv[4 * q + 1] = a.y * xv.y;
      sv[4 * q + 2] = a.z * xv.z;
      sv[4 * q + 3] = a.w * xv.w;
    }
  }
  const float gateb = gws[b];

  float hv[10];
  int hj[10];
#pragma unroll
  for (int k = 0; k < 10; ++k) { hv[k] = -1e30f; hj[k] = 0; }

  const float4* eb = reinterpret_cast<const float4*>(emb);
  for (int t = 0; t < 64; ++t) {
    const int j0 = jbase + (t << 2);
    float a0 = 0.f, a1 = 0.f, a2 = 0.f, a3 = 0.f;
    const float4* e0 = eb + ((j0 + 0) << 3);
    const float4* e1 = eb + ((j0 + 1) << 3);
    const float4* e2 = eb + ((j0 + 2) << 3);
    const float4* e3 = eb + ((j0 + 3) << 3);
#pragma unroll
    for (int q = 0; q < 8; ++q) {
      float4 v0 = e0[q], v1 = e1[q], v2 = e2[q], v3 = e3[q];
      // e-sequential FMA chains (bit-identical to R1 per-logit order)
      a0 = fmaf(sv[4 * q + 0], v0.x, a0);
      a0 = fmaf(sv[4 * q + 1], v0.y, a0);
      a0 = fmaf(sv[4 * q + 2], v0.z, a0);
      a0 = fmaf(sv[4 * q + 3], v0.w, a0);
      a1 = fmaf(sv[4 * q + 0], v1.x, a1);
      a1 = fmaf(sv[4 * q + 1], v1.y, a1);
      a1 = fmaf(sv[4 * q + 2], v1.z, a1);
      a1 = fmaf(sv[4 * q + 3], v1.w, a1);
      a2 = fmaf(sv[4 * q + 0], v2.x, a2);
      a2 = fmaf(sv[4 * q + 1], v2.y, a2);
      a2 = fmaf(sv[4 * q + 2], v2.z, a2);
      a2 = fmaf(sv[4 * q + 3], v2.w, a2);
      a3 = fmaf(sv[4 * q + 0], v3.x, a3);
      a3 = fmaf(sv[4 * q + 1], v3.y, a3);
      a3 = fmaf(sv[4 * q + 2], v3.z, a3);
      a3 = fmaf(sv[4 * q + 3], v3.w, a3);
    }

    const float thr = hv[9];
    int p0 = a0 > thr, p1 = a1 > thr, p2 = a2 > thr, p3 = a3 > thr;
    while (__any(p0 | p1 | p2 | p3)) {
      if (p0 | p1 | p2 | p3) {
        float v;
        int jn;
        if (p0) { v = a0; jn = j0; p0 = 0; }
        else if (p1) { v = a1; jn = j0 + 1; p1 = 0; }
        else if (p2) { v = a2; jn = j0 + 2; p2 = 0; }
        else { v = a3; jn = j0 + 3; p3 = 0; }
        TOP10_INSERT(v, jn);
      }
      const float nt = hv[9];
      p0 = p0 && (a0 > nt);
      p1 = p1 && (a1 > nt);
      p2 = p2 && (a2 > nt);
      p3 = p3 && (a3 > nt);
    }
  }

  // ---- cross-wave merge: odd wave publishes, even wave merges --------------
  float* mv = sb;                        // [64][10] values
  int* mj = reinterpret_cast<int*>(sb + 640);  // [64][10] indices
  if (half) {
#pragma unroll
    for (int k = 0; k < 10; ++k) {
      mv[lane * 10 + k] = hv[k];
      mj[lane * 10 + k] = hj[k];
    }
  }
  __syncthreads();
  if (half) return;  // odd waves done (no further barriers)

  // insert partner entries in desc order with strict >: on equal values the
  // lower-j (half 0 / earlier-partner) entry stays above — jax tie order.
#pragma unroll
  for (int q = 0; q < 10; ++q) {
    float v = mv[lane * 10 + q];
    int jn = mj[lane * 10 + q];
    if (v > hv[9]) TOP10_INSERT(v, jn);
  }

  // ---- epilogue: sigmoid on 10 survivors, LDS tile assembly, NT stores -----
  float oval[10];
#pragma unroll
  for (int k = 0; k < 10; ++k) oval[k] = gateb / (1.f + __expf(-hv[k]));

  nf4 z4 = {0.f, 0.f, 0.f, 0.f};
  nf4* sb4 = reinterpret_cast<nf4*>(sb);
  const int lrow = lane & 7;
  for (int t8 = 0; t8 < 8; ++t8) {  // 8 tiles x 8 rows
    asm volatile("s_waitcnt lgkmcnt(0)" ::: "memory");
#pragma unroll
    for (int k = 0; k < 16; ++k) sb4[(k << 6) + lane] = z4;
    asm volatile("s_waitcnt lgkmcnt(0)" ::: "memory");
    if ((lane >> 3) == t8) {
#pragma unroll
      for (int k = 0; k < 10; ++k) sb[(lrow << 9) + hj[k]] = oval[k];
    }
    asm volatile("s_waitcnt lgkmcnt(0)" ::: "memory");
    nf4* og = reinterpret_cast<nf4*>(out + ((size_t)r0 << 9) +
                                     ((size_t)t8 << 12));
#pragma unroll
    for (int k = 0; k < 16; ++k)
      __builtin_nontemporal_store(sb4[(k << 6) + lane], &og[(k << 6) + lane]);
  }
}

extern "C" void kernel_launch(void* const* d_in, const int* in_sizes, int n_in,
                              void* d_out, int out_size, void* d_ws,
                              size_t ws_size, hipStream_t stream) {
  const float* ctx = (const float*)d_in[0];
  const float* emb = (const float*)d_in[1];
  const float* W1 = (const float*)d_in[2];
  const float* b1 = (const float*)d_in[3];
  const float* W2 = (const float*)d_in[4];
  const float* b2 = (const float*)d_in[5];
  const float* Wg = (const float*)d_in[6];
  const float* bg = (const float*)d_in[7];
  float* out = (float*)d_out;
  float* wws = (float*)d_ws;            // 256*32 floats: c^2
  float* gws = wws + BATCH * EMBED_DIM; // 256 floats: gate

  cdm_k1<<<BATCH, 256, 0, stream>>>(ctx, W1, b1, W2, b2, Wg, bg, wws, gws);
  cdm_k2<<<1024, 256, 0, stream>>>(emb, wws, gws, out);
}